// Round 4
// baseline (1031.605 us; speedup 1.0000x reference)
//
#include <hip/hip_runtime.h>
#include <math.h>
#include <type_traits>

// ---------- bf16 helpers (intermediate buffers only; I/O is fp32) ----------

__device__ __forceinline__ float bf2f(unsigned short u) {
    union { unsigned int i; float f; } v; v.i = ((unsigned int)u) << 16; return v.f;
}
__device__ __forceinline__ unsigned short f2bf(float f) {
    union { float f_; unsigned int i; } v; v.f_ = f;
    unsigned int x = v.i;
    return (unsigned short)((x + 0x7fffu + ((x >> 16) & 1u)) >> 16);  // RNE
}
__device__ __forceinline__ float sigm(float x) { return 1.f / (1.f + expf(-x)); }
__device__ __forceinline__ float scrub(float v) {
    if (!(v == v)) return 0.f;
    return fminf(fmaxf(v, -1e30f), 1e30f);
}

typedef __attribute__((ext_vector_type(8))) short short8;
typedef __attribute__((ext_vector_type(4))) float f32x4;

// ---------------- CSR build ----------------

__global__ void k_count(const int* __restrict__ dst, int* __restrict__ indeg, int E) {
    int i = blockIdx.x * 256 + threadIdx.x;
    if (i < E) atomicAdd(&indeg[dst[i]], 1);
}

__global__ void k_dinv(const int* __restrict__ indeg, float* __restrict__ dinv, int N) {
    int i = blockIdx.x * 256 + threadIdx.x;
    if (i < N) dinv[i] = rsqrtf((float)indeg[i] + 1.0f);
}

__global__ __launch_bounds__(1024) void k_scan1(const int* __restrict__ in, int* __restrict__ out,
                                                int* __restrict__ bsum, int N) {
    __shared__ int sd[1024];
    int tid = threadIdx.x;
    int i = blockIdx.x * 1024 + tid;
    int v = (i < N) ? in[i] : 0;
    sd[tid] = v;
    __syncthreads();
    for (int s = 1; s < 1024; s <<= 1) {
        int t = (tid >= s) ? sd[tid - s] : 0;
        __syncthreads();
        sd[tid] += t;
        __syncthreads();
    }
    if (i < N) out[i] = sd[tid] - v;
    if (tid == 1023) bsum[blockIdx.x] = sd[1023];
}

__global__ void k_scan2(int* __restrict__ bsum, int nb) {
    if (threadIdx.x == 0 && blockIdx.x == 0) {
        int acc = 0;
        for (int b = 0; b < nb; ++b) { int t = bsum[b]; bsum[b] = acc; acc += t; }
        bsum[nb] = acc;
    }
}

__global__ __launch_bounds__(1024) void k_scan3(int* __restrict__ off, const int* __restrict__ bsum,
                                                int N, int nb) {
    int i = blockIdx.x * 1024 + threadIdx.x;
    if (i < N) off[i] += bsum[i >> 10];
    else if (i == N) off[N] = bsum[nb];
}

__global__ void k_fill(const int* __restrict__ src, const int* __restrict__ dst,
                       const float* __restrict__ dinv, const int* __restrict__ off,
                       int* __restrict__ cursor, int* __restrict__ csrc,
                       float* __restrict__ cw, int E) {
    int i = blockIdx.x * 256 + threadIdx.x;
    if (i >= E) return;
    int d = dst[i], s = src[i];
    int p = off[d] + atomicAdd(&cursor[d], 1);
    csrc[p] = s;
    cw[p] = dinv[s] * dinv[d];
}

// ---------------- weight transpose+convert: Wt[n][k] = bf16(W[k][n]) ----------------

__global__ void k_transpose(const float* __restrict__ W, unsigned short* __restrict__ Wt,
                            int K, int Nc) {
    int i = blockIdx.x * 256 + threadIdx.x;
    if (i < K * Nc) {
        int k = i / Nc, n = i - k * Nc;
        Wt[(size_t)n * K + k] = f2bf(W[i]);
    }
}

// ---------------- aggregation: T in {float, ushort(bf16)} input, bf16 out ----------------
// out[n] = dinv[n]^2 * H[n] + sum_{e: dst=n} w_e * H[src_e]; one wave per node

template <int F, typename T>
__global__ __launch_bounds__(256) void k_aggregate(
        const T* __restrict__ H, const float* __restrict__ dinv,
        const int* __restrict__ off, const int* __restrict__ csrc,
        const float* __restrict__ cw, unsigned short* __restrict__ out, int N) {
    constexpr int R = (F >= 64) ? (F / 64) : 1;
    int wave = (int)((blockIdx.x * 256u + threadIdx.x) >> 6);
    int lane = threadIdx.x & 63;
    if (wave >= N) return;
    int fb = (F >= 64) ? lane * R : lane;
    bool act = fb < F;
    float acc[R];
    float dn = dinv[wave], sn = dn * dn;
    #pragma unroll
    for (int j = 0; j < R; ++j) acc[j] = 0.f;
    auto ld1 = [](const T* p) -> float {
        if constexpr (std::is_same_v<T, float>) return *p;
        else return bf2f(*p);
    };
    if (act) {
        #pragma unroll
        for (int j = 0; j < R; ++j) acc[j] = ld1(H + (size_t)wave * F + fb + j) * sn;
    }
    int s0 = off[wave], s1 = off[wave + 1];
    for (int e = s0; e < s1; ++e) {
        int s = csrc[e];
        float w = cw[e];
        if (act) {
            const T* p = H + (size_t)s * F + fb;
            if constexpr (std::is_same_v<T, unsigned short>) {
                if constexpr (R == 4) {
                    ushort4 hv = *(const ushort4*)p;
                    acc[0] += bf2f(hv.x) * w; acc[1] += bf2f(hv.y) * w;
                    acc[2] += bf2f(hv.z) * w; acc[3] += bf2f(hv.w) * w;
                } else if constexpr (R == 2) {
                    ushort2 hv = *(const ushort2*)p;
                    acc[0] += bf2f(hv.x) * w; acc[1] += bf2f(hv.y) * w;
                } else {
                    acc[0] += bf2f(*p) * w;
                }
            } else {
                #pragma unroll
                for (int j = 0; j < R; ++j) acc[j] += p[j] * w;
            }
        }
    }
    if (act) {
        #pragma unroll
        for (int j = 0; j < R; ++j) out[(size_t)wave * F + fb + j] = f2bf(acc[j]);
    }
}

// ---------------- MFMA GEMM: C = relu(A[M,K] @ W[K,Nc] + b), A/Wt bf16, bias fp32 ----------------
// 4 waves/block; wave does 16 rows x 64 cols. A-frag: A[m=lane&15][k=(lane>>4)*8+j];
// B-frag: Wt[n=lane&15][same k]; C/D: col=lane&15, row=(lane>>4)*4+reg.
// POOL=1: relu + per-block LDS reduction over rows, then atomicAdd to pooled[batch*512+col].

template <int POOL>
__global__ __launch_bounds__(256) void k_gemm(
        const unsigned short* __restrict__ A, const unsigned short* __restrict__ Wt,
        const float* __restrict__ bias, unsigned short* __restrict__ C,
        float* __restrict__ pooled, const int* __restrict__ batch,
        int M, int K, int Nc) {
    __shared__ float pacc[2][64];
    __shared__ int sbat[64];
    int tid = threadIdx.x;
    int lane = tid & 63, wv = tid >> 6;
    int r = lane & 15, q = lane >> 4;
    int rowB0 = blockIdx.y * 64;            // block's first row
    int row0 = rowB0 + wv * 16;             // wave's first row
    int col0 = blockIdx.x * 64;
    if (POOL) {
        if (tid < 64) {
            int rr = rowB0 + tid; if (rr > M - 1) rr = M - 1;
            sbat[tid] = batch[rr];
        }
        if (tid < 128) pacc[tid >> 6][tid & 63] = 0.f;
        __syncthreads();
    }
    int rowA = row0 + r; if (rowA > M - 1) rowA = M - 1;
    const short8* Ap  = (const short8*)(A + (size_t)rowA * K) + q;
    const short8* Bp0 = (const short8*)(Wt + (size_t)(col0 +  0 + r) * K) + q;
    const short8* Bp1 = (const short8*)(Wt + (size_t)(col0 + 16 + r) * K) + q;
    const short8* Bp2 = (const short8*)(Wt + (size_t)(col0 + 32 + r) * K) + q;
    const short8* Bp3 = (const short8*)(Wt + (size_t)(col0 + 48 + r) * K) + q;
    f32x4 acc[4] = {{0.f,0.f,0.f,0.f},{0.f,0.f,0.f,0.f},{0.f,0.f,0.f,0.f},{0.f,0.f,0.f,0.f}};
    int ksteps = K >> 5;
    for (int kc = 0; kc < ksteps; ++kc) {
        short8 a = Ap[kc * 4];
        acc[0] = __builtin_amdgcn_mfma_f32_16x16x32_bf16(a, Bp0[kc * 4], acc[0], 0, 0, 0);
        acc[1] = __builtin_amdgcn_mfma_f32_16x16x32_bf16(a, Bp1[kc * 4], acc[1], 0, 0, 0);
        acc[2] = __builtin_amdgcn_mfma_f32_16x16x32_bf16(a, Bp2[kc * 4], acc[2], 0, 0, 0);
        acc[3] = __builtin_amdgcn_mfma_f32_16x16x32_bf16(a, Bp3[kc * 4], acc[3], 0, 0, 0);
    }
    if (POOL) {
        int gmin = sbat[0], gmax = sbat[63];
        bool fast = (gmax - gmin) <= 1;
        #pragma unroll
        for (int t = 0; t < 4; ++t) {
            int cl = t * 16 + r;
            float bv = bias[col0 + cl];
            #pragma unroll
            for (int j = 0; j < 4; ++j) {
                int row = row0 + q * 4 + j;
                if (row < M) {
                    float v = fmaxf(scrub(acc[t][j] + bv), 0.f);
                    int g = sbat[row - rowB0];
                    if (fast) atomicAdd(&pacc[g - gmin][cl], v);
                    else      atomicAdd(&pooled[(size_t)g * 512 + col0 + cl], v);
                }
            }
        }
        __syncthreads();
        if (fast) {
            int ng = gmax - gmin + 1;
            if (tid < 64 * ng) {
                int gg = tid >> 6, cl = tid & 63;
                atomicAdd(&pooled[(size_t)(gmin + gg) * 512 + col0 + cl], pacc[gg][cl]);
            }
        }
    } else {
        #pragma unroll
        for (int t = 0; t < 4; ++t) {
            int col = col0 + t * 16 + r;
            float bv = bias[col];
            #pragma unroll
            for (int j = 0; j < 4; ++j) {
                int row = row0 + q * 4 + j;
                if (row < M) {
                    float v = fmaxf(scrub(acc[t][j] + bv), 0.f);
                    C[(size_t)row * Nc + col] = f2bf(v);
                }
            }
        }
    }
}

// ---------------- graph segment bounds (batch sorted) ----------------

__global__ void k_bounds(const int* __restrict__ batch, int* __restrict__ gstart,
                         int* __restrict__ gend, int N) {
    int i = blockIdx.x * 256 + threadIdx.x;
    if (i >= N) return;
    int g = batch[i];
    if (i == 0 || batch[i - 1] != g) gstart[g] = i;
    if (i == N - 1 || batch[i + 1] != g) gend[g] = i + 1;
}

// ---------------- fused head (all fp32): mean + LSTM0 + LSTM1 + projection ----------------
// h0=c0=0 => gates = x @ Wih.T + bih + bhh; f-gate dead; c = i*g; h = o*tanh(c)

__device__ __forceinline__ float dotf(const float* __restrict__ w,
                                      const float* __restrict__ x, int K) {
    float a = 0.f;
    for (int k = 0; k < K; k += 4) {
        float4 wv = *(const float4*)(w + k);
        a += wv.x * x[k] + wv.y * x[k + 1] + wv.z * x[k + 2] + wv.w * x[k + 3];
    }
    return a;
}

__global__ __launch_bounds__(256) void k_head(
        const float* __restrict__ pooledSum,
        const int* __restrict__ gstart, const int* __restrict__ gend,
        const float* __restrict__ Wih0, const float* __restrict__ bih0,
        const float* __restrict__ bhh0,
        const float* __restrict__ Wih1, const float* __restrict__ bih1,
        const float* __restrict__ bhh1,
        const float* __restrict__ Wp, const float* __restrict__ bp,
        float* __restrict__ out) {
    __shared__ float sx[512];
    __shared__ float sh[256];
    int g = blockIdx.x, tid = threadIdx.x;
    float cnt = (float)(gend[g] - gstart[g]);
    float inv = 1.f / fmaxf(cnt, 1.f);
    sx[tid]       = scrub(pooledSum[g * 512 + tid]) * inv;
    sx[tid + 256] = scrub(pooledSum[g * 512 + 256 + tid]) * inv;
    __syncthreads();

    float ai = bih0[tid]       + bhh0[tid];
    float ag = bih0[tid + 512] + bhh0[tid + 512];
    float ao = bih0[tid + 768] + bhh0[tid + 768];
    ai += dotf(Wih0 + (size_t)tid * 512, sx, 512);
    ag += dotf(Wih0 + (size_t)(tid + 512) * 512, sx, 512);
    ao += dotf(Wih0 + (size_t)(tid + 768) * 512, sx, 512);
    float c0 = sigm(ai) * tanhf(ag);
    float h1 = sigm(ao) * tanhf(c0);
    __syncthreads();
    sh[tid] = h1;
    __syncthreads();

    ai = bih1[tid]       + bhh1[tid];
    ag = bih1[tid + 512] + bhh1[tid + 512];
    ao = bih1[tid + 768] + bhh1[tid + 768];
    ai += dotf(Wih1 + (size_t)tid * 256, sh, 256);
    ag += dotf(Wih1 + (size_t)(tid + 512) * 256, sh, 256);
    ao += dotf(Wih1 + (size_t)(tid + 768) * 256, sh, 256);
    float c1 = sigm(ai) * tanhf(ag);
    float h2 = sigm(ao) * tanhf(c1);
    __syncthreads();
    sx[tid] = h2;
    __syncthreads();

    float o0 = bp[tid]       + dotf(Wp + (size_t)tid * 256, sx, 256);
    float o1 = bp[tid + 256] + dotf(Wp + (size_t)(tid + 256) * 256, sx, 256);
    out[g * 512 + tid]       = o0;
    out[g * 512 + 256 + tid] = o1;
}

// ---------------- launch ----------------

extern "C" void kernel_launch(void* const* d_in, const int* in_sizes, int n_in,
                              void* d_out, int out_size, void* d_ws, size_t ws_size,
                              hipStream_t stream) {
    const float* x     = (const float*)d_in[0];
    const int*   eidx  = (const int*)d_in[1];
    const int*   batch = (const int*)d_in[2];
    const float* W1 = (const float*)d_in[3];  const float* b1 = (const float*)d_in[4];
    const float* W2 = (const float*)d_in[5];  const float* b2 = (const float*)d_in[6];
    const float* W3 = (const float*)d_in[7];  const float* b3 = (const float*)d_in[8];
    const float* Wih0 = (const float*)d_in[9];
    const float* bih0 = (const float*)d_in[11];
    const float* bhh0 = (const float*)d_in[12];
    const float* Wih1 = (const float*)d_in[13];
    const float* bih1 = (const float*)d_in[15];
    const float* bhh1 = (const float*)d_in[16];
    const float* Wp = (const float*)d_in[17]; const float* bp = (const float*)d_in[18];
    float* out = (float*)d_out;

    const int N = in_sizes[0] / 32;
    const int E = in_sizes[1] / 2;
    const int* src = eidx;
    const int* dst = eidx + E;

    char* w = (char*)d_ws;
    auto alloc = [&](size_t bytes) {
        char* p = w;
        w += (bytes + 255) & ~(size_t)255;
        return p;
    };
    unsigned short* buf1 = (unsigned short*)alloc((size_t)N * 256 * 2);   // 51.2 MB
    unsigned short* buf2 = (unsigned short*)alloc((size_t)N * 256 * 2);   // 51.2 MB
    unsigned short* Wt1  = (unsigned short*)alloc(128 * 32 * 2);
    unsigned short* Wt2  = (unsigned short*)alloc(256 * 128 * 2);
    unsigned short* Wt3  = (unsigned short*)alloc(512 * 256 * 2);
    int*   indeg  = (int*)alloc((size_t)N * 4);
    int*   off    = (int*)alloc((size_t)(N + 1) * 4);
    int*   cursor = (int*)alloc((size_t)N * 4);
    float* dinv   = (float*)alloc((size_t)N * 4);
    int*   csrc   = (int*)alloc((size_t)E * 4);
    float* cw     = (float*)alloc((size_t)E * 4);
    int*   bsum   = (int*)alloc(256 * 4);
    int*   gstart = (int*)alloc(64 * 4);
    int*   gend   = (int*)alloc(64 * 4);
    float* pooled = (float*)alloc(64 * 512 * 4);

    hipMemsetAsync(indeg, 0, (size_t)N * 4, stream);
    hipMemsetAsync(cursor, 0, (size_t)N * 4, stream);
    hipMemsetAsync(gstart, 0, 64 * 4, stream);
    hipMemsetAsync(gend, 0, 64 * 4, stream);
    hipMemsetAsync(pooled, 0, 64 * 512 * 4, stream);

    k_count<<<(E + 255) / 256, 256, 0, stream>>>(dst, indeg, E);
    k_dinv<<<(N + 255) / 256, 256, 0, stream>>>(indeg, dinv, N);
    int nb = (N + 1023) / 1024;
    k_scan1<<<nb, 1024, 0, stream>>>(indeg, off, bsum, N);
    k_scan2<<<1, 64, 0, stream>>>(bsum, nb);
    k_scan3<<<(N + 1 + 1023) / 1024, 1024, 0, stream>>>(off, bsum, N, nb);
    k_fill<<<(E + 255) / 256, 256, 0, stream>>>(src, dst, dinv, off, cursor, csrc, cw, E);

    k_transpose<<<(32 * 128 + 255) / 256, 256, 0, stream>>>(W1, Wt1, 32, 128);
    k_transpose<<<(128 * 256 + 255) / 256, 256, 0, stream>>>(W2, Wt2, 128, 256);
    k_transpose<<<(256 * 512 + 255) / 256, 256, 0, stream>>>(W3, Wt3, 256, 512);
    k_bounds<<<(N + 255) / 256, 256, 0, stream>>>(batch, gstart, gend, N);

    int aggBlocks = (N + 3) / 4;
    int rowTiles = (N + 63) / 64;

    // layer 1: agg(x fp32) -> buf1[N,32] bf16; gemm -> buf2[N,128] bf16
    k_aggregate<32, float><<<aggBlocks, 256, 0, stream>>>(x, dinv, off, csrc, cw, buf1, N);
    {
        dim3 grid(128 / 64, rowTiles);
        k_gemm<0><<<grid, 256, 0, stream>>>(buf1, Wt1, b1, buf2, nullptr, nullptr, N, 32, 128);
    }
    // layer 2
    k_aggregate<128, unsigned short><<<aggBlocks, 256, 0, stream>>>(buf2, dinv, off, csrc, cw, buf1, N);
    {
        dim3 grid(256 / 64, rowTiles);
        k_gemm<0><<<grid, 256, 0, stream>>>(buf1, Wt2, b2, buf2, nullptr, nullptr, N, 128, 256);
    }
    // layer 3: agg -> buf1[N,256]; gemm fused with relu + LDS-pooled atomics
    k_aggregate<256, unsigned short><<<aggBlocks, 256, 0, stream>>>(buf2, dinv, off, csrc, cw, buf1, N);
    {
        dim3 grid(512 / 64, rowTiles);
        k_gemm<1><<<grid, 256, 0, stream>>>(buf1, Wt3, b3, nullptr, pooled, batch, N, 256, 512);
    }

    k_head<<<64, 256, 0, stream>>>(pooled, gstart, gend,
                                   Wih0, bih0, bhh0, Wih1, bih1, bhh1, Wp, bp, out);
}

// Round 5
// 997.449 us; speedup vs baseline: 1.0342x; 1.0342x over previous
//
#include <hip/hip_runtime.h>
#include <math.h>
#include <type_traits>

// ---------- bf16 helpers (intermediate buffers only; I/O is fp32) ----------

__device__ __forceinline__ float bf2f(unsigned short u) {
    union { unsigned int i; float f; } v; v.i = ((unsigned int)u) << 16; return v.f;
}
__device__ __forceinline__ unsigned short f2bf(float f) {
    union { float f_; unsigned int i; } v; v.f_ = f;
    unsigned int x = v.i;
    return (unsigned short)((x + 0x7fffu + ((x >> 16) & 1u)) >> 16);  // RNE
}
__device__ __forceinline__ float sigm(float x) { return 1.f / (1.f + expf(-x)); }

typedef __attribute__((ext_vector_type(8))) short short8;
typedef __attribute__((ext_vector_type(4))) float f32x4;

// ---------------- CSR build ----------------

__global__ void k_count(const int* __restrict__ dst, int* __restrict__ indeg, int E) {
    int i = blockIdx.x * 256 + threadIdx.x;
    if (i < E) atomicAdd(&indeg[dst[i]], 1);
}

__global__ void k_dinv(const int* __restrict__ indeg, float* __restrict__ dinv, int N) {
    int i = blockIdx.x * 256 + threadIdx.x;
    if (i < N) dinv[i] = rsqrtf((float)indeg[i] + 1.0f);
}

__global__ __launch_bounds__(1024) void k_scan1(const int* __restrict__ in, int* __restrict__ out,
                                                int* __restrict__ bsum, int N) {
    __shared__ int sd[1024];
    int tid = threadIdx.x;
    int i = blockIdx.x * 1024 + tid;
    int v = (i < N) ? in[i] : 0;
    sd[tid] = v;
    __syncthreads();
    for (int s = 1; s < 1024; s <<= 1) {
        int t = (tid >= s) ? sd[tid - s] : 0;
        __syncthreads();
        sd[tid] += t;
        __syncthreads();
    }
    if (i < N) out[i] = sd[tid] - v;
    if (tid == 1023) bsum[blockIdx.x] = sd[1023];
}

__global__ void k_scan2(int* __restrict__ bsum, int nb) {
    if (threadIdx.x == 0 && blockIdx.x == 0) {
        int acc = 0;
        for (int b = 0; b < nb; ++b) { int t = bsum[b]; bsum[b] = acc; acc += t; }
        bsum[nb] = acc;
    }
}

__global__ __launch_bounds__(1024) void k_scan3(int* __restrict__ off, const int* __restrict__ bsum,
                                                int N, int nb) {
    int i = blockIdx.x * 1024 + threadIdx.x;
    if (i < N) off[i] += bsum[i >> 10];
    else if (i == N) off[N] = bsum[nb];
}

__global__ void k_fill(const int* __restrict__ src, const int* __restrict__ dst,
                       const float* __restrict__ dinv, const int* __restrict__ off,
                       int* __restrict__ cursor, int* __restrict__ csrc,
                       float* __restrict__ cw, int E) {
    int i = blockIdx.x * 256 + threadIdx.x;
    if (i >= E) return;
    int d = dst[i], s = src[i];
    int p = off[d] + atomicAdd(&cursor[d], 1);
    csrc[p] = s;
    cw[p] = dinv[s] * dinv[d];
}

// ---------------- weight transpose+convert: Wt[n][k] = bf16(W[k][n]) ----------------

__global__ void k_transpose(const float* __restrict__ W, unsigned short* __restrict__ Wt,
                            int K, int Nc) {
    int i = blockIdx.x * 256 + threadIdx.x;
    if (i < K * Nc) {
        int k = i / Nc, n = i - k * Nc;
        Wt[(size_t)n * K + k] = f2bf(W[i]);
    }
}

// ---------------- aggregation: T in {float, ushort(bf16)} input, bf16 out ----------------
// out[n] = dinv[n]^2 * H[n] + sum_{e: dst=n} w_e * H[src_e]; one wave per node

template <int F, typename T>
__global__ __launch_bounds__(256) void k_aggregate(
        const T* __restrict__ H, const float* __restrict__ dinv,
        const int* __restrict__ off, const int* __restrict__ csrc,
        const float* __restrict__ cw, unsigned short* __restrict__ out, int N) {
    constexpr int R = (F >= 64) ? (F / 64) : 1;
    int wave = (int)((blockIdx.x * 256u + threadIdx.x) >> 6);
    int lane = threadIdx.x & 63;
    if (wave >= N) return;
    int fb = (F >= 64) ? lane * R : lane;
    bool act = fb < F;
    float acc[R];
    float dn = dinv[wave], sn = dn * dn;
    #pragma unroll
    for (int j = 0; j < R; ++j) acc[j] = 0.f;
    auto ld1 = [](const T* p) -> float {
        if constexpr (std::is_same_v<T, float>) return *p;
        else return bf2f(*p);
    };
    if (act) {
        #pragma unroll
        for (int j = 0; j < R; ++j) acc[j] = ld1(H + (size_t)wave * F + fb + j) * sn;
    }
    int s0 = off[wave], s1 = off[wave + 1];
    for (int e = s0; e < s1; ++e) {
        int s = csrc[e];
        float w = cw[e];
        if (act) {
            const T* p = H + (size_t)s * F + fb;
            if constexpr (std::is_same_v<T, unsigned short>) {
                if constexpr (R == 4) {
                    ushort4 hv = *(const ushort4*)p;
                    acc[0] += bf2f(hv.x) * w; acc[1] += bf2f(hv.y) * w;
                    acc[2] += bf2f(hv.z) * w; acc[3] += bf2f(hv.w) * w;
                } else if constexpr (R == 2) {
                    ushort2 hv = *(const ushort2*)p;
                    acc[0] += bf2f(hv.x) * w; acc[1] += bf2f(hv.y) * w;
                } else {
                    acc[0] += bf2f(*p) * w;
                }
            } else {
                #pragma unroll
                for (int j = 0; j < R; ++j) acc[j] += p[j] * w;
            }
        }
    }
    if (act) {
        #pragma unroll
        for (int j = 0; j < R; ++j) out[(size_t)wave * F + fb + j] = f2bf(acc[j]);
    }
}

// ---------------- A-stationary MFMA GEMM ----------------
// C = relu(A[M,K] @ W[K,NC] + b). One block per 64-row stripe; the block loops
// over ALL column tiles with A-fragments register-resident (A fetched once).
// A-frag: A[m=lane&15][k=(lane>>4)*8+j]; B-frag: Wt[n=lane&15][same k];
// C/D: col=lane&15, row=(lane>>4)*4+reg.
// POOL=1: relu + LDS-pool over rows (batch sorted => <=2 graphs/stripe fast path).

template <int K, int NC, int POOL>
__global__ __launch_bounds__(256) void k_gemm(
        const unsigned short* __restrict__ A, const unsigned short* __restrict__ Wt,
        const float* __restrict__ bias, unsigned short* __restrict__ C,
        float* __restrict__ pooled, const int* __restrict__ batch, int M) {
    constexpr int KST = K / 32;
    constexpr int NT = NC / 64;
    __shared__ float pacc[POOL ? 2 : 1][POOL ? NC : 1];
    __shared__ int sbat[POOL ? 64 : 1];
    int tid = threadIdx.x;
    int lane = tid & 63, wv = tid >> 6;
    int r = lane & 15, q = lane >> 4;
    int rowB0 = blockIdx.x * 64;
    int row0 = rowB0 + wv * 16;
    if (POOL) {
        if (tid < 64) {
            int rr = rowB0 + tid; if (rr > M - 1) rr = M - 1;
            sbat[tid] = batch[rr];
        }
        for (int i = tid; i < 2 * NC; i += 256) pacc[i / NC][i % NC] = 0.f;
        __syncthreads();
    }
    int rowA = row0 + r; if (rowA > M - 1) rowA = M - 1;
    const short8* Ap = (const short8*)(A + (size_t)rowA * K) + q;
    short8 aF[KST];
    #pragma unroll
    for (int kc = 0; kc < KST; ++kc) aF[kc] = Ap[kc * 4];

    int gmin = 0; bool fast = false;
    if (POOL) { gmin = sbat[0]; fast = (sbat[63] - gmin) <= 1; }

    for (int t = 0; t < NT; ++t) {
        int col0 = t * 64;
        const short8* Bp0 = (const short8*)(Wt + (size_t)(col0 +  0 + r) * K) + q;
        const short8* Bp1 = (const short8*)(Wt + (size_t)(col0 + 16 + r) * K) + q;
        const short8* Bp2 = (const short8*)(Wt + (size_t)(col0 + 32 + r) * K) + q;
        const short8* Bp3 = (const short8*)(Wt + (size_t)(col0 + 48 + r) * K) + q;
        f32x4 acc[4] = {{0.f,0.f,0.f,0.f},{0.f,0.f,0.f,0.f},{0.f,0.f,0.f,0.f},{0.f,0.f,0.f,0.f}};
        #pragma unroll
        for (int kc = 0; kc < KST; ++kc) {
            acc[0] = __builtin_amdgcn_mfma_f32_16x16x32_bf16(aF[kc], Bp0[kc * 4], acc[0], 0, 0, 0);
            acc[1] = __builtin_amdgcn_mfma_f32_16x16x32_bf16(aF[kc], Bp1[kc * 4], acc[1], 0, 0, 0);
            acc[2] = __builtin_amdgcn_mfma_f32_16x16x32_bf16(aF[kc], Bp2[kc * 4], acc[2], 0, 0, 0);
            acc[3] = __builtin_amdgcn_mfma_f32_16x16x32_bf16(aF[kc], Bp3[kc * 4], acc[3], 0, 0, 0);
        }
        #pragma unroll
        for (int tt = 0; tt < 4; ++tt) {
            int col = col0 + tt * 16 + r;
            float bv = bias[col];
            #pragma unroll
            for (int j = 0; j < 4; ++j) {
                int row = row0 + q * 4 + j;
                if (row < M) {
                    float v = fmaxf(acc[tt][j] + bv, 0.f);
                    if (POOL) {
                        int g = sbat[row - rowB0];
                        if (fast) atomicAdd(&pacc[g - gmin][col], v);
                        else      atomicAdd(&pooled[(size_t)g * NC + col], v);
                    } else {
                        C[(size_t)row * NC + col] = f2bf(v);
                    }
                }
            }
        }
    }
    if (POOL) {
        __syncthreads();
        if (fast) {
            for (int i = tid; i < 2 * NC; i += 256) {
                int gg = i / NC, col = i % NC;
                if (gmin + gg < 64 || gg == 0)
                    atomicAdd(&pooled[(size_t)(gmin + gg) * NC + col], pacc[gg][col]);
            }
        }
    }
}

// ---------------- graph segment bounds (batch sorted) ----------------

__global__ void k_bounds(const int* __restrict__ batch, int* __restrict__ gstart,
                         int* __restrict__ gend, int N) {
    int i = blockIdx.x * 256 + threadIdx.x;
    if (i >= N) return;
    int g = batch[i];
    if (i == 0 || batch[i - 1] != g) gstart[g] = i;
    if (i == N - 1 || batch[i + 1] != g) gend[g] = i + 1;
}

// ---------------- fused head (all fp32): mean + LSTM0 + LSTM1 + projection ----------------
// h0=c0=0 => gates = x @ Wih.T + bih + bhh; f-gate dead; c = i*g; h = o*tanh(c)

__device__ __forceinline__ float dotf(const float* __restrict__ w,
                                      const float* __restrict__ x, int K) {
    float a = 0.f;
    for (int k = 0; k < K; k += 4) {
        float4 wv = *(const float4*)(w + k);
        a += wv.x * x[k] + wv.y * x[k + 1] + wv.z * x[k + 2] + wv.w * x[k + 3];
    }
    return a;
}

__global__ __launch_bounds__(256) void k_head(
        const float* __restrict__ pooledSum,
        const int* __restrict__ gstart, const int* __restrict__ gend,
        const float* __restrict__ Wih0, const float* __restrict__ bih0,
        const float* __restrict__ bhh0,
        const float* __restrict__ Wih1, const float* __restrict__ bih1,
        const float* __restrict__ bhh1,
        const float* __restrict__ Wp, const float* __restrict__ bp,
        float* __restrict__ out) {
    __shared__ float sx[512];
    __shared__ float sh[256];
    int g = blockIdx.x, tid = threadIdx.x;
    float cnt = (float)(gend[g] - gstart[g]);
    float inv = 1.f / fmaxf(cnt, 1.f);
    sx[tid]       = pooledSum[g * 512 + tid] * inv;
    sx[tid + 256] = pooledSum[g * 512 + 256 + tid] * inv;
    __syncthreads();

    float ai = bih0[tid]       + bhh0[tid];
    float ag = bih0[tid + 512] + bhh0[tid + 512];
    float ao = bih0[tid + 768] + bhh0[tid + 768];
    ai += dotf(Wih0 + (size_t)tid * 512, sx, 512);
    ag += dotf(Wih0 + (size_t)(tid + 512) * 512, sx, 512);
    ao += dotf(Wih0 + (size_t)(tid + 768) * 512, sx, 512);
    float c0 = sigm(ai) * tanhf(ag);
    float h1 = sigm(ao) * tanhf(c0);
    __syncthreads();
    sh[tid] = h1;
    __syncthreads();

    ai = bih1[tid]       + bhh1[tid];
    ag = bih1[tid + 512] + bhh1[tid + 512];
    ao = bih1[tid + 768] + bhh1[tid + 768];
    ai += dotf(Wih1 + (size_t)tid * 256, sh, 256);
    ag += dotf(Wih1 + (size_t)(tid + 512) * 256, sh, 256);
    ao += dotf(Wih1 + (size_t)(tid + 768) * 256, sh, 256);
    float c1 = sigm(ai) * tanhf(ag);
    float h2 = sigm(ao) * tanhf(c1);
    __syncthreads();
    sx[tid] = h2;
    __syncthreads();

    float o0 = bp[tid]       + dotf(Wp + (size_t)tid * 256, sx, 256);
    float o1 = bp[tid + 256] + dotf(Wp + (size_t)(tid + 256) * 256, sx, 256);
    out[g * 512 + tid]       = o0;
    out[g * 512 + 256 + tid] = o1;
}

// ---------------- launch ----------------

extern "C" void kernel_launch(void* const* d_in, const int* in_sizes, int n_in,
                              void* d_out, int out_size, void* d_ws, size_t ws_size,
                              hipStream_t stream) {
    const float* x     = (const float*)d_in[0];
    const int*   eidx  = (const int*)d_in[1];
    const int*   batch = (const int*)d_in[2];
    const float* W1 = (const float*)d_in[3];  const float* b1 = (const float*)d_in[4];
    const float* W2 = (const float*)d_in[5];  const float* b2 = (const float*)d_in[6];
    const float* W3 = (const float*)d_in[7];  const float* b3 = (const float*)d_in[8];
    const float* Wih0 = (const float*)d_in[9];
    const float* bih0 = (const float*)d_in[11];
    const float* bhh0 = (const float*)d_in[12];
    const float* Wih1 = (const float*)d_in[13];
    const float* bih1 = (const float*)d_in[15];
    const float* bhh1 = (const float*)d_in[16];
    const float* Wp = (const float*)d_in[17]; const float* bp = (const float*)d_in[18];
    float* out = (float*)d_out;

    const int N = in_sizes[0] / 32;
    const int E = in_sizes[1] / 2;
    const int* src = eidx;
    const int* dst = eidx + E;

    char* w = (char*)d_ws;
    auto alloc = [&](size_t bytes) {
        char* p = w;
        w += (bytes + 255) & ~(size_t)255;
        return p;
    };
    unsigned short* buf1 = (unsigned short*)alloc((size_t)N * 256 * 2);   // 51.2 MB
    unsigned short* buf2 = (unsigned short*)alloc((size_t)N * 256 * 2);   // 51.2 MB
    unsigned short* Wt1  = (unsigned short*)alloc(128 * 32 * 2);
    unsigned short* Wt2  = (unsigned short*)alloc(256 * 128 * 2);
    unsigned short* Wt3  = (unsigned short*)alloc(512 * 256 * 2);
    int*   indeg  = (int*)alloc((size_t)N * 4);
    int*   off    = (int*)alloc((size_t)(N + 1) * 4);
    int*   cursor = (int*)alloc((size_t)N * 4);
    float* dinv   = (float*)alloc((size_t)N * 4);
    int*   csrc   = (int*)alloc((size_t)E * 4);
    float* cw     = (float*)alloc((size_t)E * 4);
    int*   bsum   = (int*)alloc(256 * 4);
    int*   gstart = (int*)alloc(64 * 4);
    int*   gend   = (int*)alloc(64 * 4);
    float* pooled = (float*)alloc(64 * 512 * 4);

    hipMemsetAsync(indeg, 0, (size_t)N * 4, stream);
    hipMemsetAsync(cursor, 0, (size_t)N * 4, stream);
    hipMemsetAsync(gstart, 0, 64 * 4, stream);
    hipMemsetAsync(gend, 0, 64 * 4, stream);
    hipMemsetAsync(pooled, 0, 64 * 512 * 4, stream);

    k_count<<<(E + 255) / 256, 256, 0, stream>>>(dst, indeg, E);
    k_dinv<<<(N + 255) / 256, 256, 0, stream>>>(indeg, dinv, N);
    int nb = (N + 1023) / 1024;
    k_scan1<<<nb, 1024, 0, stream>>>(indeg, off, bsum, N);
    k_scan2<<<1, 64, 0, stream>>>(bsum, nb);
    k_scan3<<<(N + 1 + 1023) / 1024, 1024, 0, stream>>>(off, bsum, N, nb);
    k_fill<<<(E + 255) / 256, 256, 0, stream>>>(src, dst, dinv, off, cursor, csrc, cw, E);

    k_transpose<<<(32 * 128 + 255) / 256, 256, 0, stream>>>(W1, Wt1, 32, 128);
    k_transpose<<<(128 * 256 + 255) / 256, 256, 0, stream>>>(W2, Wt2, 128, 256);
    k_transpose<<<(256 * 512 + 255) / 256, 256, 0, stream>>>(W3, Wt3, 256, 512);
    k_bounds<<<(N + 255) / 256, 256, 0, stream>>>(batch, gstart, gend, N);

    int aggBlocks = (N + 3) / 4;
    int rowTiles = (N + 63) / 64;

    // layer 1: agg(x fp32) -> buf1[N,32] bf16; gemm -> buf2[N,128] bf16
    k_aggregate<32, float><<<aggBlocks, 256, 0, stream>>>(x, dinv, off, csrc, cw, buf1, N);
    k_gemm<32, 128, 0><<<rowTiles, 256, 0, stream>>>(buf1, Wt1, b1, buf2, nullptr, nullptr, N);
    // layer 2
    k_aggregate<128, unsigned short><<<aggBlocks, 256, 0, stream>>>(buf2, dinv, off, csrc, cw, buf1, N);
    k_gemm<128, 256, 0><<<rowTiles, 256, 0, stream>>>(buf1, Wt2, b2, buf2, nullptr, nullptr, N);
    // layer 3: agg -> buf1[N,256]; gemm fused with relu + LDS-pooled reduction
    k_aggregate<256, unsigned short><<<aggBlocks, 256, 0, stream>>>(buf2, dinv, off, csrc, cw, buf1, N);
    k_gemm<256, 512, 1><<<rowTiles, 256, 0, stream>>>(buf1, Wt3, b3, nullptr, pooled, batch, N);

    k_head<<<64, 256, 0, stream>>>(pooled, gstart, gend,
                                   Wih0, bih0, bhh0, Wih1, bih1, bhh1, Wp, bp, out);
}